// Round 10
// baseline (406.285 us; speedup 1.0000x reference)
//
#include <hip/hip_runtime.h>

typedef _Float16 v8hf __attribute__((ext_vector_type(8)));
typedef float    v4f  __attribute__((ext_vector_type(4)));

#define MFMA16(a, b, c) __builtin_amdgcn_mfma_f32_16x16x32_f16((a), (b), (c), 0, 0, 0)

#define TT 512
#define BT 16       // batch rows per pipeline (= MFMA N)
#define NTH 256     // 4 waves: w0=L1, w1=L2, w2=L3+head, w3=flush
#define KS 2.8853900817779268f   // 2*log2(e), folded into weights+biases
#define CL 13.8498724f           // 4.8 * KS

// dynamic LDS map (bytes):
//   h1 ring: 4 slots x 4096  @ 0      (slot = lane*16 + kt*1024)
//   h2 ring: 4 slots x 2048  @ 16384
//   xst:     513 t-slots x 64 @ 24576  (u32 f16-pair per (t,b))
//   oring:   [b][64][2] f32   @ 57408  (512 B per b)
#define H1R 0u
#define H2R 16384u
#define XST 24576u
#define ORG 57408u
#define SMEMB 65600

extern __shared__ __align__(16) char SM[];

// tanh of pre-scaled z (z = KS * preact): 4 exp2 + 1 rcp; clamp |x|<=4.8.
__device__ __forceinline__ v4f tanh4s(v4f z) {
    float z0 = __builtin_amdgcn_fmed3f(z[0], -CL, CL);
    float z1 = __builtin_amdgcn_fmed3f(z[1], -CL, CL);
    float z2 = __builtin_amdgcn_fmed3f(z[2], -CL, CL);
    float z3 = __builtin_amdgcn_fmed3f(z[3], -CL, CL);
    float a0 = __builtin_amdgcn_exp2f(z0) + 1.f;
    float a1 = __builtin_amdgcn_exp2f(z1) + 1.f;
    float a2 = __builtin_amdgcn_exp2f(z2) + 1.f;
    float a3 = __builtin_amdgcn_exp2f(z3) + 1.f;
    float P = a0 * a1, Q = a2 * a3;
    float R = __builtin_amdgcn_rcpf(P * Q);
    float iP = Q * R, iQ = P * R;
    v4f t;
    t[0] = 1.f - 2.f * (a1 * iP);
    t[1] = 1.f - 2.f * (a0 * iP);
    t[2] = 1.f - 2.f * (a3 * iQ);
    t[3] = 1.f - 2.f * (a2 * iQ);
    return t;
}

__device__ __forceinline__ unsigned pk2h(float a, float b) {
    union { _Float16 h[2]; unsigned u; } x;
    x.h[0] = (_Float16)a; x.h[1] = (_Float16)b;
    return x.u;
}
__device__ __forceinline__ v8hf mk8(unsigned a, unsigned b, unsigned c, unsigned d) {
    union { unsigned u[4]; v8hf h; } x;
    x.u[0] = a; x.u[1] = b; x.u[2] = c; x.u[3] = d;
    return x.h;
}

__global__ __launch_bounds__(NTH, 1)
void rnn3_ws(const float* __restrict__ xg,
             const float* __restrict__ Wih1, const float* __restrict__ Whh1,
             const float* __restrict__ bih1, const float* __restrict__ bhh1,
             const float* __restrict__ Wih2, const float* __restrict__ Whh2,
             const float* __restrict__ bih2, const float* __restrict__ bhh2,
             const float* __restrict__ Wih3, const float* __restrict__ Whh3,
             const float* __restrict__ bih3, const float* __restrict__ bhh3,
             const float* __restrict__ Wo1,  const float* __restrict__ bo1,
             const float* __restrict__ Wo2,  const float* __restrict__ bo2,
             float* __restrict__ outg)
{
    const int tid   = threadIdx.x;
    const int lane  = tid & 63;
    const int wid   = tid >> 6;
    const int col   = lane & 15;   // operand-own-dim index / batch in B-frags
    const int g     = lane >> 4;   // k-group
    const int bbase = blockIdx.x * BT;

    // ---- init: stage x as f16 pairs [t][b]; zero pad slot 512 ----
    for (int i = tid; i < BT * TT; i += NTH) {
        const int b = i >> 9, t = i & 511;
        float2 xv = *(const float2*)(xg + (size_t)(bbase + b) * (TT * 2) + 2 * t);
        *(unsigned*)(SM + XST + (unsigned)t * 64u + (unsigned)b * 4u) = pk2h(xv.x, xv.y);
    }
    if (tid < 16) *(unsigned*)(SM + XST + 512u * 64u + (unsigned)tid * 4u) = 0u;
    __syncthreads();

    // k-slot permutation (identical for A and B operands, so it cancels):
    //   logical_k(kt, g, e) = 32*kt + 16*(e>>2) + 4*g + (e&3)
    auto ldA = [&](const float* W, int rows, int cols, int jg, int kt) -> v8hf {
        v8hf r;
        #pragma unroll
        for (int e = 0; e < 8; ++e) {
            const int kl = 32 * kt + 16 * (e >> 2) + 4 * g + (e & 3);
            float v = (jg < rows && kl < cols) ? W[jg * cols + kl] * KS : 0.f;
            r[e] = (_Float16)v;
        }
        return r;
    };
    auto ldA1 = [&](int jg, int kt) -> v8hf {   // Whh1 + x-weights at logical 112,113
        v8hf r;
        #pragma unroll
        for (int e = 0; e < 8; ++e) {
            const int kl = 32 * kt + 16 * (e >> 2) + 4 * g + (e & 3);
            float v = 0.f;
            if (jg < 100) {
                if (kl < 100)       v = Whh1[jg * 100 + kl];
                else if (kl == 112) v = Wih1[jg * 2];
                else if (kl == 113) v = Wih1[jg * 2 + 1];
            }
            r[e] = (_Float16)(v * KS);
        }
        return r;
    };
    auto mkbias = [&](const float* bi, const float* bh, int n, int t) -> v4f {
        v4f b;
        #pragma unroll
        for (int i = 0; i < 4; ++i) {
            const int j = 16 * t + 4 * g + i;
            b[i] = (j < n) ? KS * (bi[j] + bh[j]) : 0.f;
        }
        return b;
    };

    const v8hf z8 = (v8hf)(_Float16)0.f;

    if (wid == 0) {
        // ---------------- wave 0: layer 1, fully in-register ----------------
        v8hf W1f[7][4]; v4f B1[7];
        #pragma unroll
        for (int t = 0; t < 7; ++t) {
            #pragma unroll
            for (int kt = 0; kt < 4; ++kt) W1f[t][kt] = ldA1(16 * t + col, kt);
            B1[t] = mkbias(bih1, bhh1, 100, t);
        }
        v8hf H0 = z8, H1 = z8, H2 = z8, H3;
        {
            unsigned x0 = *(const unsigned*)(SM + XST + (unsigned)col * 4u);
            H3 = mk8(0u, 0u, (g == 0) ? x0 : 0u, 0u);
        }
        for (int u = 0; u <= 258; ++u) {
            #pragma unroll
            for (int sub = 0; sub < 2; ++sub) {
                const int s = 2 * u + sub;
                if (s < TT) {
                    unsigned xn = 0u;
                    if (s < TT - 1)
                        xn = *(const unsigned*)(SM + XST + (unsigned)(s + 1) * 64u + (unsigned)col * 4u);
                    unsigned lo[7], hi[7];
                    #pragma unroll
                    for (int t = 0; t < 7; ++t) {
                        v4f p = B1[t];
                        p = MFMA16(W1f[t][0], H0, p);
                        p = MFMA16(W1f[t][1], H1, p);
                        p = MFMA16(W1f[t][2], H2, p);
                        p = MFMA16(W1f[t][3], H3, p);
                        v4f r = tanh4s(p);
                        lo[t] = pk2h(r[0], r[1]); hi[t] = pk2h(r[2], r[3]);
                    }
                    H0 = mk8(lo[0], hi[0], lo[1], hi[1]);
                    H1 = mk8(lo[2], hi[2], lo[3], hi[3]);
                    H2 = mk8(lo[4], hi[4], lo[5], hi[5]);
                    H3 = mk8(lo[6], hi[6], (g == 0) ? xn : 0u, 0u);
                    char* wb = SM + H1R + (unsigned)(s & 3) * 4096u + (unsigned)lane * 16u;
                    *(v8hf*)(wb)        = H0;
                    *(v8hf*)(wb + 1024) = H1;
                    *(v8hf*)(wb + 2048) = H2;
                    *(v8hf*)(wb + 3072) = H3;
                }
            }
            __syncthreads();
        }
    } else if (wid == 1) {
        // ---------------- wave 1: layer 2 at lag 2 ----------------
        v8hf Wi2[4][4], Wh2[4][2]; v4f B2[4];
        #pragma unroll
        for (int t = 0; t < 4; ++t) {
            #pragma unroll
            for (int kt = 0; kt < 4; ++kt) Wi2[t][kt] = ldA(Wih2, 60, 100, 16 * t + col, kt);
            Wh2[t][0] = ldA(Whh2, 60, 60, 16 * t + col, 0);
            Wh2[t][1] = ldA(Whh2, 60, 60, 16 * t + col, 1);
            B2[t] = mkbias(bih2, bhh2, 60, t);
        }
        v8hf Sa = z8, Sb = z8;
        for (int u = 0; u <= 258; ++u) {
            #pragma unroll
            for (int sub = 0; sub < 2; ++sub) {
                const int s1 = 2 * u + sub - 2;
                if (s1 >= 0 && s1 < TT) {
                    const char* rb = SM + H1R + (unsigned)(s1 & 3) * 4096u + (unsigned)lane * 16u;
                    v8hf G0 = *(const v8hf*)(rb);
                    v8hf G1 = *(const v8hf*)(rb + 1024);
                    v8hf G2 = *(const v8hf*)(rb + 2048);
                    v8hf G3 = *(const v8hf*)(rb + 3072);
                    unsigned lo[4], hi[4];
                    #pragma unroll
                    for (int t = 0; t < 4; ++t) {
                        v4f p = B2[t];
                        p = MFMA16(Wi2[t][0], G0, p);
                        p = MFMA16(Wi2[t][1], G1, p);
                        p = MFMA16(Wi2[t][2], G2, p);
                        p = MFMA16(Wi2[t][3], G3, p);
                        p = MFMA16(Wh2[t][0], Sa, p);
                        p = MFMA16(Wh2[t][1], Sb, p);
                        v4f r = tanh4s(p);
                        lo[t] = pk2h(r[0], r[1]); hi[t] = pk2h(r[2], r[3]);
                    }
                    Sa = mk8(lo[0], hi[0], lo[1], hi[1]);
                    Sb = mk8(lo[2], hi[2], lo[3], hi[3]);
                    char* wb = SM + H2R + (unsigned)(s1 & 3) * 2048u + (unsigned)lane * 16u;
                    *(v8hf*)(wb)        = Sa;
                    *(v8hf*)(wb + 1024) = Sb;
                }
            }
            __syncthreads();
        }
    } else if (wid == 2) {
        // ---------------- wave 2: layer 3 + head at lag 4 ----------------
        v8hf Wi3[2][2], Wh3[2], We; v4f B3[2], Bh;
        #pragma unroll
        for (int t = 0; t < 2; ++t) {
            Wi3[t][0] = ldA(Wih3, 30, 60, 16 * t + col, 0);
            Wi3[t][1] = ldA(Wih3, 30, 60, 16 * t + col, 1);
            Wh3[t]    = ldA(Whh3, 30, 30, 16 * t + col, 0);
            B3[t] = mkbias(bih3, bhh3, 30, t);
        }
        #pragma unroll
        for (int e = 0; e < 8; ++e) {   // W_eff = Wo2 @ Wo1 (2 x 30), unscaled
            const int kl = 16 * (e >> 2) + 4 * g + (e & 3);
            float v = 0.f;
            if (col < 2 && kl < 30) {
                #pragma unroll
                for (int uu = 0; uu < 10; ++uu) v += Wo2[col * 10 + uu] * Wo1[uu * 30 + kl];
            }
            We[e] = (_Float16)v;
        }
        #pragma unroll
        for (int i = 0; i < 4; ++i) {
            float bv = 0.f;
            if (g == 0 && i < 2) {
                bv = bo2[i];
                #pragma unroll
                for (int uu = 0; uu < 10; ++uu) bv += Wo2[i * 10 + uu] * bo1[uu];
            }
            Bh[i] = bv;
        }
        v8hf S3 = z8;
        for (int u = 0; u <= 258; ++u) {
            #pragma unroll
            for (int sub = 0; sub < 2; ++sub) {
                const int s2 = 2 * u + sub - 4;
                if (s2 >= 0 && s2 < TT) {
                    const char* rb = SM + H2R + (unsigned)(s2 & 3) * 2048u + (unsigned)lane * 16u;
                    v8hf G0 = *(const v8hf*)(rb);
                    v8hf G1 = *(const v8hf*)(rb + 1024);
                    unsigned lo[2], hi[2];
                    #pragma unroll
                    for (int t = 0; t < 2; ++t) {
                        v4f p = B3[t];
                        p = MFMA16(Wi3[t][0], G0, p);
                        p = MFMA16(Wi3[t][1], G1, p);
                        p = MFMA16(Wh3[t], S3, p);
                        v4f r = tanh4s(p);
                        lo[t] = pk2h(r[0], r[1]); hi[t] = pk2h(r[2], r[3]);
                    }
                    S3 = mk8(lo[0], hi[0], lo[1], hi[1]);
                    v4f o = Bh;
                    o = MFMA16(We, S3, o);
                    if (g == 0)
                        *(float2*)(SM + ORG + (unsigned)col * 512u + (unsigned)(s2 & 63) * 8u) =
                            make_float2(o[0], o[1]);
                }
            }
            __syncthreads();
        }
    } else {
        // ---------------- wave 3: coalesced output flush ----------------
        for (int u = 0; u <= 258; ++u) {
            if (u >= 18 && ((u - 18) & 15) == 0) {
                const int tbase = 2 * u - 36;          // multiple of 32, 0..480
                const unsigned rb = ORG + (((unsigned)tbase & 63u) >> 1) * 16u;
                #pragma unroll
                for (int jj = 0; jj < 4; ++jj) {
                    const int f = lane + 64 * jj;
                    const int b = f >> 4, k = f & 15;
                    float4 v = *(const float4*)(SM + rb + (unsigned)b * 512u + (unsigned)k * 16u);
                    *(float4*)(outg + ((size_t)(bbase + b) * TT + tbase) * 2 + 4 * k) = v;
                }
            }
            __syncthreads();
        }
    }
}

extern "C" void kernel_launch(void* const* d_in, const int* in_sizes, int n_in,
                              void* d_out, int out_size, void* d_ws, size_t ws_size,
                              hipStream_t stream) {
    (void)in_sizes; (void)n_in; (void)d_ws; (void)ws_size; (void)out_size;
    const float* x     = (const float*)d_in[0];
    const float* W_ih1 = (const float*)d_in[1];
    const float* W_hh1 = (const float*)d_in[2];
    const float* b_ih1 = (const float*)d_in[3];
    const float* b_hh1 = (const float*)d_in[4];
    const float* W_ih2 = (const float*)d_in[5];
    const float* W_hh2 = (const float*)d_in[6];
    const float* b_ih2 = (const float*)d_in[7];
    const float* b_hh2 = (const float*)d_in[8];
    const float* W_ih3 = (const float*)d_in[9];
    const float* W_hh3 = (const float*)d_in[10];
    const float* b_ih3 = (const float*)d_in[11];
    const float* b_hh3 = (const float*)d_in[12];
    const float* W_o1  = (const float*)d_in[13];
    const float* b_o1  = (const float*)d_in[14];
    const float* W_o2  = (const float*)d_in[15];
    const float* b_o2  = (const float*)d_in[16];
    float* out = (float*)d_out;

    hipFuncSetAttribute((const void*)rnn3_ws,
                        hipFuncAttributeMaxDynamicSharedMemorySize, SMEMB);
    rnn3_ws<<<2048 / BT, NTH, SMEMB, stream>>>(
        x, W_ih1, W_hh1, b_ih1, b_hh1,
        W_ih2, W_hh2, b_ih2, b_hh2,
        W_ih3, W_hh3, b_ih3, b_hh3,
        W_o1, b_o1, W_o2, b_o2, out);
}

// Round 11
// 333.325 us; speedup vs baseline: 1.2189x; 1.2189x over previous
//
#include <hip/hip_runtime.h>

typedef _Float16 v8hf __attribute__((ext_vector_type(8)));
typedef float    v4f  __attribute__((ext_vector_type(4)));

#define MFMA16(a, b, c) __builtin_amdgcn_mfma_f32_16x16x32_f16((a), (b), (c), 0, 0, 0)

#define TT 512
#define BT 16       // batch rows (= MFMA N)
#define NTH 512     // 8 waves; SIMD pairs (0,4)(1,5)(2,6)(3,7)
#define KS 2.8853900817779268f   // 2*log2(e), folded into weights+biases
#define CL 13.8498724f           // 4.8 * KS

// LDS (bytes):
//   h1 ring: 2 blocks x 4096 @ 0     (block + slotReg*1024 + lane*16)
//   h2 ring: 2 blocks x 2048 @ 8192
//   xst:     513 x 64        @ 12288 (u32 f16-pair per (t,b))
//   oring:   [b][64][2] f32  @ 45120 (512 B per b)
#define H1R 0u
#define H2R 8192u
#define XST 12288u
#define ORG 45120u

__shared__ __align__(16) char SM[53312];

// tanh of pre-scaled z (z = KS*preact): 4 exp2 + 1 rcp; clamp |x|<=4.8 (err 1.35e-4).
__device__ __forceinline__ v4f tanh4s(v4f z) {
    float z0 = __builtin_amdgcn_fmed3f(z[0], -CL, CL);
    float z1 = __builtin_amdgcn_fmed3f(z[1], -CL, CL);
    float z2 = __builtin_amdgcn_fmed3f(z[2], -CL, CL);
    float z3 = __builtin_amdgcn_fmed3f(z[3], -CL, CL);
    float a0 = __builtin_amdgcn_exp2f(z0) + 1.f;
    float a1 = __builtin_amdgcn_exp2f(z1) + 1.f;
    float a2 = __builtin_amdgcn_exp2f(z2) + 1.f;
    float a3 = __builtin_amdgcn_exp2f(z3) + 1.f;
    float P = a0 * a1, Q = a2 * a3;
    float R = __builtin_amdgcn_rcpf(P * Q);
    float iP = Q * R, iQ = P * R;
    v4f t;
    t[0] = 1.f - 2.f * (a1 * iP);
    t[1] = 1.f - 2.f * (a0 * iP);
    t[2] = 1.f - 2.f * (a3 * iQ);
    t[3] = 1.f - 2.f * (a2 * iQ);
    return t;
}

__device__ __forceinline__ unsigned pk2h(float a, float b) {
    union { _Float16 h[2]; unsigned u; } x;
    x.h[0] = (_Float16)a; x.h[1] = (_Float16)b;
    return x.u;
}
__device__ __forceinline__ v8hf mk8(unsigned a, unsigned b, unsigned c, unsigned d) {
    union { unsigned u[4]; v8hf h; } x;
    x.u[0] = a; x.u[1] = b; x.u[2] = c; x.u[3] = d;
    return x.h;
}

__global__ __launch_bounds__(NTH, 1)
void rnn3_sw(const float* __restrict__ xg,
             const float* __restrict__ Wih1, const float* __restrict__ Whh1,
             const float* __restrict__ bih1, const float* __restrict__ bhh1,
             const float* __restrict__ Wih2, const float* __restrict__ Whh2,
             const float* __restrict__ bih2, const float* __restrict__ bhh2,
             const float* __restrict__ Wih3, const float* __restrict__ Whh3,
             const float* __restrict__ bih3, const float* __restrict__ bhh3,
             const float* __restrict__ Wo1,  const float* __restrict__ bo1,
             const float* __restrict__ Wo2,  const float* __restrict__ bo2,
             float* __restrict__ outg)
{
    const int tid   = threadIdx.x;
    const int lane  = tid & 63;
    const int wid   = tid >> 6;
    const int col   = lane & 15;   // batch index in B/C frags
    const int g     = lane >> 4;   // k-group / C row-group
    const int bbase = blockIdx.x * BT;
    const unsigned l16 = (unsigned)lane * 16u;

    // ---- init: zero rings, stage x as f16 pairs [t][b] (slot 512 zeroed) ----
    {
        float4 z = {0.f, 0.f, 0.f, 0.f};
        for (int i = tid; i < 768; i += NTH) ((float4*)SM)[i] = z;   // bytes [0,12288)
        for (int i = tid; i < BT * TT; i += NTH) {
            const int b = i >> 9, t = i & 511;
            float2 xv = *(const float2*)(xg + (size_t)(bbase + b) * (TT * 2) + 2 * t);
            *(unsigned*)(SM + XST + (unsigned)t * 64u + (unsigned)b * 4u) = pk2h(xv.x, xv.y);
        }
        if (tid < 16) *(unsigned*)(SM + XST + 512u * 64u + (unsigned)tid * 4u) = 0u;
    }

    // ---- weight fragments. k-slot map (same for A and B, so HW perm cancels):
    //      logical_k(slotReg r, g, e) = 32*r + 16*(e>>2) + 4*g + (e&3)
    v8hf WF[12];
    #pragma unroll
    for (int i = 0; i < 12; ++i) WF[i] = (v8hf)(_Float16)0.f;
    v4f BB0 = {0.f,0.f,0.f,0.f}, BB1 = {0.f,0.f,0.f,0.f}, BH = {0.f,0.f,0.f,0.f};
    v8hf ST = (v8hf)(_Float16)0.f;   // own persistent state slot

    auto ldA = [&](const float* W, int rows, int cols, int jg, int kt) -> v8hf {
        v8hf r;
        #pragma unroll
        for (int e = 0; e < 8; ++e) {
            const int kl = 32 * kt + 16 * (e >> 2) + 4 * g + (e & 3);
            float v = (jg < rows && kl < cols) ? W[jg * cols + kl] * KS : 0.f;
            r[e] = (_Float16)v;
        }
        return r;
    };
    auto ldA1 = [&](int jg, int kt) -> v8hf {   // Whh1 + x weights at logical 112,113
        v8hf r;
        #pragma unroll
        for (int e = 0; e < 8; ++e) {
            const int kl = 32 * kt + 16 * (e >> 2) + 4 * g + (e & 3);
            float v = 0.f;
            if (jg < 100) {
                if (kl < 100)       v = Whh1[jg * 100 + kl];
                else if (kl == 112) v = Wih1[jg * 2];
                else if (kl == 113) v = Wih1[jg * 2 + 1];
            }
            r[e] = (_Float16)(v * KS);
        }
        return r;
    };
    auto mkbias = [&](const float* bi, const float* bh, int n, int t) -> v4f {
        v4f b;
        #pragma unroll
        for (int i = 0; i < 4; ++i) {
            const int j = 16 * t + 4 * g + i;
            b[i] = (j < n) ? KS * (bi[j] + bh[j]) : 0.f;
        }
        return b;
    };

    if (wid < 3) {                       // L1 tiles 2w, 2w+1 -> h1 slot w
        const int tA = 2 * wid;
        #pragma unroll
        for (int kt = 0; kt < 4; ++kt) {
            WF[kt]     = ldA1(16 * tA + col, kt);
            WF[4 + kt] = ldA1(16 * tA + 16 + col, kt);
        }
        BB0 = mkbias(bih1, bhh1, 100, tA);
        BB1 = mkbias(bih1, bhh1, 100, tA + 1);
    } else if (wid == 3) {               // L1 tile 6 + x -> h1 slot 3
        #pragma unroll
        for (int kt = 0; kt < 4; ++kt) WF[kt] = ldA1(96 + col, kt);
        BB0 = mkbias(bih1, bhh1, 100, 6);
    } else if (wid < 6) {                // L2 tiles 2(w-4), 2(w-4)+1 -> h2 slot (w-4)
        const int tA = 2 * (wid - 4);
        #pragma unroll
        for (int kt = 0; kt < 4; ++kt) {
            WF[kt]     = ldA(Wih2, 60, 100, 16 * tA + col, kt);
            WF[4 + kt] = ldA(Wih2, 60, 100, 16 * tA + 16 + col, kt);
        }
        WF[8]  = ldA(Whh2, 60, 60, 16 * tA + col, 0);
        WF[9]  = ldA(Whh2, 60, 60, 16 * tA + col, 1);
        WF[10] = ldA(Whh2, 60, 60, 16 * tA + 16 + col, 0);
        WF[11] = ldA(Whh2, 60, 60, 16 * tA + 16 + col, 1);
        BB0 = mkbias(bih2, bhh2, 60, tA);
        BB1 = mkbias(bih2, bhh2, 60, tA + 1);
    } else if (wid == 6) {               // L3 (2 tiles) + head
        WF[0] = ldA(Wih3, 30, 60, col, 0);       WF[1] = ldA(Wih3, 30, 60, col, 1);
        WF[2] = ldA(Wih3, 30, 60, col + 16, 0);  WF[3] = ldA(Wih3, 30, 60, col + 16, 1);
        WF[4] = ldA(Whh3, 30, 30, col, 0);       WF[5] = ldA(Whh3, 30, 30, col + 16, 0);
        #pragma unroll
        for (int e = 0; e < 8; ++e) {    // W_eff = Wo2 @ Wo1 (2 x 30), UNscaled
            const int kl = 16 * (e >> 2) + 4 * g + (e & 3);
            float v = 0.f;
            if (col < 2 && kl < 30) {
                #pragma unroll
                for (int u = 0; u < 10; ++u) v += Wo2[col * 10 + u] * Wo1[u * 30 + kl];
            }
            WF[6][e] = (_Float16)v;
        }
        BB0 = mkbias(bih3, bhh3, 30, 0);
        BB1 = mkbias(bih3, bhh3, 30, 1);
        #pragma unroll
        for (int i = 0; i < 4; ++i) {
            float bv = 0.f;
            if (g == 0 && i < 2) {
                bv = bo2[i];
                #pragma unroll
                for (int u = 0; u < 10; ++u) bv += Wo2[i * 10 + u] * bo1[u];
            }
            BH[i] = bv;
        }
    }

    __syncthreads();
    // x(0) into h1 ring block 1 (rp of phase 0), slot 3, u32[2] of g==0 lanes
    if (tid < 16)
        *(unsigned*)(SM + H1R + 4096u + 3072u + (unsigned)tid * 16u + 8u) =
            *(const unsigned*)(SM + XST + (unsigned)tid * 4u);
    if (wid == 3) {   // own ST must match: (0,0,x0|g==0,0)
        unsigned x0 = *(const unsigned*)(SM + XST + (unsigned)col * 4u);
        ST = mk8(0u, 0u, (g == 0) ? x0 : 0u, 0u);
    }
    __syncthreads();

    auto flushfn = [&](int tbase) {      // 32 head steps, coalesced float4
        const unsigned rb = ORG + (((unsigned)tbase & 63u) >> 1) * 16u;
        #pragma unroll
        for (int jj = 0; jj < 4; ++jj) {
            const int f = lane + 64 * jj;
            const int b = f >> 4, k = f & 15;
            float4 v = *(const float4*)(SM + rb + (unsigned)b * 512u + (unsigned)k * 16u);
            *(float4*)(outg + ((size_t)(bbase + b) * TT + tbase) * 2 + 4 * k) = v;
        }
    };

    unsigned rO1 = H1R + 4096u, wO1 = H1R;
    unsigned rO2 = H2R + 2048u, wO2 = H2R;
    const v4f z4 = {0.f, 0.f, 0.f, 0.f};

    // phase s: L1(s) | L2(s-1) | L3+head(s-2) | flush; one barrier per phase
    for (int s = 0; s < TT + 2; ++s) {
        if (wid == 0) {
            if (s < TT) {
                v8hf S1 = *(const v8hf*)(SM + rO1 + 1024u + l16);
                v8hf S2 = *(const v8hf*)(SM + rO1 + 2048u + l16);
                v8hf S3 = *(const v8hf*)(SM + rO1 + 3072u + l16);
                v4f p = BB0, q = z4;
                p = MFMA16(WF[0], ST, p); q = MFMA16(WF[1], S1, q);
                p = MFMA16(WF[2], S2, p); q = MFMA16(WF[3], S3, q);
                v4f r0 = tanh4s(p + q);
                p = BB1; q = z4;
                p = MFMA16(WF[4], ST, p); q = MFMA16(WF[5], S1, q);
                p = MFMA16(WF[6], S2, p); q = MFMA16(WF[7], S3, q);
                v4f r1 = tanh4s(p + q);
                ST = mk8(pk2h(r0[0], r0[1]), pk2h(r0[2], r0[3]),
                         pk2h(r1[0], r1[1]), pk2h(r1[2], r1[3]));
                *(v8hf*)(SM + wO1 + l16) = ST;
            }
        } else if (wid == 1) {
            if (s < TT) {
                v8hf S0 = *(const v8hf*)(SM + rO1 + l16);
                v8hf S2 = *(const v8hf*)(SM + rO1 + 2048u + l16);
                v8hf S3 = *(const v8hf*)(SM + rO1 + 3072u + l16);
                v4f p = BB0, q = z4;
                p = MFMA16(WF[0], S0, p); q = MFMA16(WF[1], ST, q);
                p = MFMA16(WF[2], S2, p); q = MFMA16(WF[3], S3, q);
                v4f r0 = tanh4s(p + q);
                p = BB1; q = z4;
                p = MFMA16(WF[4], S0, p); q = MFMA16(WF[5], ST, q);
                p = MFMA16(WF[6], S2, p); q = MFMA16(WF[7], S3, q);
                v4f r1 = tanh4s(p + q);
                ST = mk8(pk2h(r0[0], r0[1]), pk2h(r0[2], r0[3]),
                         pk2h(r1[0], r1[1]), pk2h(r1[2], r1[3]));
                *(v8hf*)(SM + wO1 + 1024u + l16) = ST;
            }
        } else if (wid == 2) {
            if (s < TT) {
                v8hf S0 = *(const v8hf*)(SM + rO1 + l16);
                v8hf S1 = *(const v8hf*)(SM + rO1 + 1024u + l16);
                v8hf S3 = *(const v8hf*)(SM + rO1 + 3072u + l16);
                v4f p = BB0, q = z4;
                p = MFMA16(WF[0], S0, p); q = MFMA16(WF[1], S1, q);
                p = MFMA16(WF[2], ST, p); q = MFMA16(WF[3], S3, q);
                v4f r0 = tanh4s(p + q);
                p = BB1; q = z4;
                p = MFMA16(WF[4], S0, p); q = MFMA16(WF[5], S1, q);
                p = MFMA16(WF[6], ST, p); q = MFMA16(WF[7], S3, q);
                v4f r1 = tanh4s(p + q);
                ST = mk8(pk2h(r0[0], r0[1]), pk2h(r0[2], r0[3]),
                         pk2h(r1[0], r1[1]), pk2h(r1[2], r1[3]));
                *(v8hf*)(SM + wO1 + 2048u + l16) = ST;
            }
        } else if (wid == 3) {
            if (s < TT) {
                v8hf S0 = *(const v8hf*)(SM + rO1 + l16);
                v8hf S1 = *(const v8hf*)(SM + rO1 + 1024u + l16);
                v8hf S2 = *(const v8hf*)(SM + rO1 + 2048u + l16);
                v4f p = BB0, q = z4;
                p = MFMA16(WF[0], S0, p); q = MFMA16(WF[1], S1, q);
                p = MFMA16(WF[2], S2, p); q = MFMA16(WF[3], ST, q);
                v4f r0 = tanh4s(p + q);
                unsigned xn = *(const unsigned*)(SM + XST + (unsigned)(s + 1) * 64u + (unsigned)col * 4u);
                ST = mk8(pk2h(r0[0], r0[1]), pk2h(r0[2], r0[3]),
                         (g == 0) ? xn : 0u, 0u);
                *(v8hf*)(SM + wO1 + 3072u + l16) = ST;
            }
        } else if (wid == 4) {
            if (s >= 1 && s <= TT) {
                v8hf G0 = *(const v8hf*)(SM + rO1 + l16);
                v8hf G1 = *(const v8hf*)(SM + rO1 + 1024u + l16);
                v8hf G2 = *(const v8hf*)(SM + rO1 + 2048u + l16);
                v8hf G3 = *(const v8hf*)(SM + rO1 + 3072u + l16);
                v8hf SB = *(const v8hf*)(SM + rO2 + 1024u + l16);
                v4f p = BB0, q = z4;
                p = MFMA16(WF[0], G0, p); q = MFMA16(WF[1], G1, q);
                p = MFMA16(WF[2], G2, p); q = MFMA16(WF[3], G3, q);
                p = MFMA16(WF[8], ST, p); q = MFMA16(WF[9], SB, q);
                v4f r0 = tanh4s(p + q);
                p = BB1; q = z4;
                p = MFMA16(WF[4], G0, p); q = MFMA16(WF[5], G1, q);
                p = MFMA16(WF[6], G2, p); q = MFMA16(WF[7], G3, q);
                p = MFMA16(WF[10], ST, p); q = MFMA16(WF[11], SB, q);
                v4f r1 = tanh4s(p + q);
                ST = mk8(pk2h(r0[0], r0[1]), pk2h(r0[2], r0[3]),
                         pk2h(r1[0], r1[1]), pk2h(r1[2], r1[3]));
                *(v8hf*)(SM + wO2 + l16) = ST;
            }
        } else if (wid == 5) {
            if (s >= 1 && s <= TT) {
                v8hf G0 = *(const v8hf*)(SM + rO1 + l16);
                v8hf G1 = *(const v8hf*)(SM + rO1 + 1024u + l16);
                v8hf G2 = *(const v8hf*)(SM + rO1 + 2048u + l16);
                v8hf G3 = *(const v8hf*)(SM + rO1 + 3072u + l16);
                v8hf SA = *(const v8hf*)(SM + rO2 + l16);
                v4f p = BB0, q = z4;
                p = MFMA16(WF[0], G0, p); q = MFMA16(WF[1], G1, q);
                p = MFMA16(WF[2], G2, p); q = MFMA16(WF[3], G3, q);
                p = MFMA16(WF[8], SA, p); q = MFMA16(WF[9], ST, q);
                v4f r0 = tanh4s(p + q);
                p = BB1; q = z4;
                p = MFMA16(WF[4], G0, p); q = MFMA16(WF[5], G1, q);
                p = MFMA16(WF[6], G2, p); q = MFMA16(WF[7], G3, q);
                p = MFMA16(WF[10], SA, p); q = MFMA16(WF[11], ST, q);
                v4f r1 = tanh4s(p + q);
                ST = mk8(pk2h(r0[0], r0[1]), pk2h(r0[2], r0[3]),
                         pk2h(r1[0], r1[1]), pk2h(r1[2], r1[3]));
                *(v8hf*)(SM + wO2 + 1024u + l16) = ST;
            }
        } else if (wid == 6) {
            if (s >= 2) {                // t = s-2 <= 511
                v8hf G0 = *(const v8hf*)(SM + rO2 + l16);
                v8hf G1 = *(const v8hf*)(SM + rO2 + 1024u + l16);
                v4f p = BB0, q = z4;
                p = MFMA16(WF[0], G0, p); q = MFMA16(WF[1], G1, q);
                p = MFMA16(WF[4], ST, p);
                v4f r0 = tanh4s(p + q);
                p = BB1; q = z4;
                p = MFMA16(WF[2], G0, p); q = MFMA16(WF[3], G1, q);
                p = MFMA16(WF[5], ST, p);
                v4f r1 = tanh4s(p + q);
                ST = mk8(pk2h(r0[0], r0[1]), pk2h(r0[2], r0[3]),
                         pk2h(r1[0], r1[1]), pk2h(r1[2], r1[3]));
                v4f o = BH;
                o = MFMA16(WF[6], ST, o);
                if (g == 0)
                    *(float2*)(SM + ORG + (unsigned)col * 512u + ((unsigned)(s - 2) & 63u) * 8u) =
                        make_float2(o[0], o[1]);
            }
        } else {
            if (s >= 35 && ((s - 35) & 31) == 0) flushfn(s - 35);   // tbase 0..448
        }
        __syncthreads();
        rO1 ^= 4096u; wO1 ^= 4096u; rO2 ^= 2048u; wO2 ^= 2048u;
    }
    if (wid == 7) flushfn(480);   // last barrier already ordered head(480..511)
}

extern "C" void kernel_launch(void* const* d_in, const int* in_sizes, int n_in,
                              void* d_out, int out_size, void* d_ws, size_t ws_size,
                              hipStream_t stream) {
    (void)in_sizes; (void)n_in; (void)d_ws; (void)ws_size; (void)out_size;
    const float* x     = (const float*)d_in[0];
    const float* W_ih1 = (const float*)d_in[1];
    const float* W_hh1 = (const float*)d_in[2];
    const float* b_ih1 = (const float*)d_in[3];
    const float* b_hh1 = (const float*)d_in[4];
    const float* W_ih2 = (const float*)d_in[5];
    const float* W_hh2 = (const float*)d_in[6];
    const float* b_ih2 = (const float*)d_in[7];
    const float* b_hh2 = (const float*)d_in[8];
    const float* W_ih3 = (const float*)d_in[9];
    const float* W_hh3 = (const float*)d_in[10];
    const float* b_ih3 = (const float*)d_in[11];
    const float* b_hh3 = (const float*)d_in[12];
    const float* W_o1  = (const float*)d_in[13];
    const float* b_o1  = (const float*)d_in[14];
    const float* W_o2  = (const float*)d_in[15];
    const float* b_o2  = (const float*)d_in[16];
    float* out = (float*)d_out;

    rnn3_sw<<<2048 / BT, NTH, 0, stream>>>(
        x, W_ih1, W_hh1, b_ih1, b_hh1,
        W_ih2, W_hh2, b_ih2, b_hh2,
        W_ih3, W_hh3, b_ih3, b_hh3,
        W_o1, b_o1, W_o2, b_o2, out);
}

// Round 12
// 293.289 us; speedup vs baseline: 1.3853x; 1.1365x over previous
//
#include <hip/hip_runtime.h>

typedef _Float16 v8hf __attribute__((ext_vector_type(8)));
typedef float    v4f  __attribute__((ext_vector_type(4)));

#define MFMA16(a, b, c) __builtin_amdgcn_mfma_f32_16x16x32_f16((a), (b), (c), 0, 0, 0)

#define TT 512
#define BT 16       // batch rows (= MFMA N)
#define NTH 1024    // 16 thin waves, 4/SIMD
#define KS 2.8853900817779268f   // 2*log2(e), folded into weights+biases
#define CL 13.8498724f           // 4.8 * KS

// LDS (bytes). Fragment slot = 64 lanes x 16 B = 1024 B; k-map
// nu(r,g,e) = 32r + 16(e>>2) + 4g + (e&3)  (same for A and B -> HW perm cancels).
//   h1 ring: 2 blocks x 4 slots  @ 0      (k: 0..99 h1, 100..111 fake, 112..113 x)
//   h2 ring: 2 blocks x 2 slots  @ 8192
//   h3 ring: 2 blocks x 1 slot   @ 12288
//   xst:     513 x 64            @ 14336  (u32 f16-pair per (t,b))
//   oring:   [b][64][2] f32      @ 47168  (512 B per b)
#define H1R 0u
#define H2R 8192u
#define H3R 12288u
#define XST 14336u
#define ORG 47168u

__shared__ __align__(16) char SM[55360];

// tanh of pre-scaled z (z = KS*preact): 4 exp2 + 1 rcp; clamp |x|<=4.8 (err 1.35e-4).
__device__ __forceinline__ v4f tanh4s(v4f z) {
    float z0 = __builtin_amdgcn_fmed3f(z[0], -CL, CL);
    float z1 = __builtin_amdgcn_fmed3f(z[1], -CL, CL);
    float z2 = __builtin_amdgcn_fmed3f(z[2], -CL, CL);
    float z3 = __builtin_amdgcn_fmed3f(z[3], -CL, CL);
    float a0 = __builtin_amdgcn_exp2f(z0) + 1.f;
    float a1 = __builtin_amdgcn_exp2f(z1) + 1.f;
    float a2 = __builtin_amdgcn_exp2f(z2) + 1.f;
    float a3 = __builtin_amdgcn_exp2f(z3) + 1.f;
    float P = a0 * a1, Q = a2 * a3;
    float R = __builtin_amdgcn_rcpf(P * Q);
    float iP = Q * R, iQ = P * R;
    v4f t;
    t[0] = 1.f - 2.f * (a1 * iP);
    t[1] = 1.f - 2.f * (a0 * iP);
    t[2] = 1.f - 2.f * (a3 * iQ);
    t[3] = 1.f - 2.f * (a2 * iQ);
    return t;
}

__device__ __forceinline__ unsigned pk2h(float a, float b) {
    union { _Float16 h[2]; unsigned u; } x;
    x.h[0] = (_Float16)a; x.h[1] = (_Float16)b;
    return x.u;
}

__global__ __launch_bounds__(NTH, 1)
void rnn3_nu(const float* __restrict__ xg,
             const float* __restrict__ Wih1, const float* __restrict__ Whh1,
             const float* __restrict__ bih1, const float* __restrict__ bhh1,
             const float* __restrict__ Wih2, const float* __restrict__ Whh2,
             const float* __restrict__ bih2, const float* __restrict__ bhh2,
             const float* __restrict__ Wih3, const float* __restrict__ Whh3,
             const float* __restrict__ bih3, const float* __restrict__ bhh3,
             const float* __restrict__ Wo1,  const float* __restrict__ bo1,
             const float* __restrict__ Wo2,  const float* __restrict__ bo2,
             float* __restrict__ outg)
{
    const int tid   = threadIdx.x;
    const int lane  = tid & 63;
    const int wid   = tid >> 6;    // 16 waves; SIMD = wid&3
    const int col   = lane & 15;   // batch index in B/C frags
    const int g     = lane >> 4;   // k-group / C row-group
    const int bbase = blockIdx.x * BT;
    const unsigned l16 = (unsigned)lane * 16u;

    // ---- init: zero all rings [0, XST); stage x as f16 pairs [t][b] ----
    {
        float4 z = {0.f, 0.f, 0.f, 0.f};
        for (int i = tid; i < 896; i += NTH) ((float4*)SM)[i] = z;
        for (int i = tid; i < BT * TT; i += NTH) {
            const int b = i >> 9, t = i & 511;
            float2 xv = *(const float2*)(xg + (size_t)(bbase + b) * (TT * 2) + 2 * t);
            *(unsigned*)(SM + XST + (unsigned)t * 64u + (unsigned)b * 4u) = pk2h(xv.x, xv.y);
        }
        if (tid < 16) *(unsigned*)(SM + XST + 512u * 64u + (unsigned)tid * 4u) = 0u;
    }

    // ---- weight fragments (registers), nu k-map ----
    v8hf WF[6];
    #pragma unroll
    for (int i = 0; i < 6; ++i) WF[i] = (v8hf)(_Float16)0.f;
    v4f BB0 = {0.f, 0.f, 0.f, 0.f}, BH = {0.f, 0.f, 0.f, 0.f};

    auto ldA = [&](const float* W, int rows, int cols, int jg, int kt) -> v8hf {
        v8hf r;
        #pragma unroll
        for (int e = 0; e < 8; ++e) {
            const int kl = 32 * kt + 16 * (e >> 2) + 4 * g + (e & 3);
            float v = (jg < rows && kl < cols) ? W[jg * cols + kl] * KS : 0.f;
            r[e] = (_Float16)v;
        }
        return r;
    };
    auto ldA1 = [&](int jg, int kt) -> v8hf {   // Whh1 + x weights at logical 112,113
        v8hf r;
        #pragma unroll
        for (int e = 0; e < 8; ++e) {
            const int kl = 32 * kt + 16 * (e >> 2) + 4 * g + (e & 3);
            float v = 0.f;
            if (jg < 100) {
                if (kl < 100)       v = Whh1[jg * 100 + kl];
                else if (kl == 112) v = Wih1[jg * 2];
                else if (kl == 113) v = Wih1[jg * 2 + 1];
            }
            r[e] = (_Float16)(v * KS);
        }
        return r;
    };
    auto mkbias = [&](const float* bi, const float* bh, int n, int t) -> v4f {
        v4f b;
        #pragma unroll
        for (int i = 0; i < 4; ++i) {
            const int j = 16 * t + 4 * g + i;
            b[i] = (j < n) ? KS * (bi[j] + bh[j]) : 0.f;
        }
        return b;
    };

    if (wid < 7) {                       // L1 tile wid
        #pragma unroll
        for (int kt = 0; kt < 4; ++kt) WF[kt] = ldA1(16 * wid + col, kt);
        BB0 = mkbias(bih1, bhh1, 100, wid);
    } else if (wid >= 8 && wid < 12) {   // L2 tile wid-8
        const int j = 16 * (wid - 8) + col;
        #pragma unroll
        for (int kt = 0; kt < 4; ++kt) WF[kt] = ldA(Wih2, 60, 100, j, kt);
        WF[4] = ldA(Whh2, 60, 60, j, 0);
        WF[5] = ldA(Whh2, 60, 60, j, 1);
        BB0 = mkbias(bih2, bhh2, 60, wid - 8);
    } else if (wid == 12 || wid == 13) { // L3 tile wid-12
        const int j = 16 * (wid - 12) + col;
        WF[0] = ldA(Wih3, 30, 60, j, 0);
        WF[1] = ldA(Wih3, 30, 60, j, 1);
        WF[2] = ldA(Whh3, 30, 30, j, 0);
        BB0 = mkbias(bih3, bhh3, 30, wid - 12);
    } else if (wid == 14) {              // head: W_eff = Wo2 @ Wo1 (2 x 30), UNscaled
        #pragma unroll
        for (int e = 0; e < 8; ++e) {
            const int kl = 16 * (e >> 2) + 4 * g + (e & 3);
            float v = 0.f;
            if (col < 2 && kl < 30) {
                #pragma unroll
                for (int u = 0; u < 10; ++u) v += Wo2[col * 10 + u] * Wo1[u * 30 + kl];
            }
            WF[0][e] = (_Float16)v;
        }
        #pragma unroll
        for (int i = 0; i < 4; ++i) {
            float bv = 0.f;
            if (g == 0 && i < 2) {
                bv = bo2[i];
                #pragma unroll
                for (int u = 0; u < 10; ++u) bv += Wo2[i * 10 + u] * bo1[u];
            }
            BH[i] = bv;
        }
    }                                     // wid 7: x-stage; wid 15: flush

    __syncthreads();
    // x(0) into h1 ring block 1 (rp of phase 0), slot 3, u32[2] (g==0 lanes)
    if (tid < 16)
        *(unsigned*)(SM + H1R + 4096u + 3072u + (unsigned)tid * 16u + 8u) =
            *(const unsigned*)(SM + XST + (unsigned)tid * 4u);
    __syncthreads();

    auto flushfn = [&](int tbase) {      // 32 head steps, coalesced float4
        const unsigned rb = ORG + (((unsigned)tbase & 63u) >> 1) * 16u;
        #pragma unroll
        for (int jj = 0; jj < 4; ++jj) {
            const int f = lane + 64 * jj;
            const int b = f >> 4, k = f & 15;
            float4 v = *(const float4*)(SM + rb + (unsigned)b * 512u + (unsigned)k * 16u);
            *(float4*)(outg + ((size_t)(bbase + b) * TT + tbase) * 2 + 4 * k) = v;
        }
    };

    unsigned rO1 = H1R + 4096u, wO1 = H1R;
    unsigned rO2 = H2R + 2048u, wO2 = H2R;
    unsigned rO3 = H3R + 1024u, wO3 = H3R;
    const v4f z4 = {0.f, 0.f, 0.f, 0.f};

    // phase s: L1(s) | L2(s-1) | L3(s-2) | head(s-3) | x_{s+1} | flush
    for (int s = 0; s < TT + 3; ++s) {
        if (wid < 7) {
            if (s < TT) {
                v8hf S0 = *(const v8hf*)(SM + rO1 + l16);
                v8hf S1 = *(const v8hf*)(SM + rO1 + 1024u + l16);
                v8hf S2 = *(const v8hf*)(SM + rO1 + 2048u + l16);
                v8hf S3 = *(const v8hf*)(SM + rO1 + 3072u + l16);
                v4f p = BB0, q = z4;
                p = MFMA16(WF[0], S0, p); q = MFMA16(WF[1], S1, q);
                p = MFMA16(WF[2], S2, p); q = MFMA16(WF[3], S3, q);
                v4f r = tanh4s(p + q);
                uint2 wv; wv.x = pk2h(r[0], r[1]); wv.y = pk2h(r[2], r[3]);
                *(uint2*)(SM + wO1 + (unsigned)(wid >> 1) * 1024u + l16
                             + (unsigned)(wid & 1) * 8u) = wv;
            }
        } else if (wid == 7) {
            if (s < TT - 1) {            // stage x_{s+1} into h1[wp] slot3 u32[2]
                unsigned xv = *(const unsigned*)(SM + XST + (unsigned)(s + 1) * 64u
                                                    + (unsigned)col * 4u);
                uint2 wv; wv.x = (g == 0) ? xv : 0u; wv.y = 0u;
                *(uint2*)(SM + wO1 + 3072u + l16 + 8u) = wv;
            }
        } else if (wid < 12) {
            if (s >= 1 && s <= TT) {
                v8hf G0 = *(const v8hf*)(SM + rO1 + l16);
                v8hf G1 = *(const v8hf*)(SM + rO1 + 1024u + l16);
                v8hf G2 = *(const v8hf*)(SM + rO1 + 2048u + l16);
                v8hf G3 = *(const v8hf*)(SM + rO1 + 3072u + l16);
                v8hf H0 = *(const v8hf*)(SM + rO2 + l16);
                v8hf H1 = *(const v8hf*)(SM + rO2 + 1024u + l16);
                v4f p = BB0, q = z4, r2 = z4;
                p  = MFMA16(WF[0], G0, p);
                q  = MFMA16(WF[1], G1, q);
                r2 = MFMA16(WF[4], H0, r2);
                p  = MFMA16(WF[2], G2, p);
                q  = MFMA16(WF[3], G3, q);
                r2 = MFMA16(WF[5], H1, r2);
                v4f r = tanh4s(p + q + r2);
                const int t2 = wid - 8;
                uint2 wv; wv.x = pk2h(r[0], r[1]); wv.y = pk2h(r[2], r[3]);
                *(uint2*)(SM + wO2 + (unsigned)(t2 >> 1) * 1024u + l16
                             + (unsigned)(t2 & 1) * 8u) = wv;
            }
        } else if (wid < 14) {
            if (s >= 2 && s <= TT + 1) {
                v8hf G0 = *(const v8hf*)(SM + rO2 + l16);
                v8hf G1 = *(const v8hf*)(SM + rO2 + 1024u + l16);
                v8hf C0 = *(const v8hf*)(SM + rO3 + l16);
                v4f p = BB0, q = z4, r2 = z4;
                p  = MFMA16(WF[0], G0, p);
                q  = MFMA16(WF[1], G1, q);
                r2 = MFMA16(WF[2], C0, r2);
                v4f r = tanh4s(p + q + r2);
                const int t3 = wid - 12;
                uint2 wv; wv.x = pk2h(r[0], r[1]); wv.y = pk2h(r[2], r[3]);
                *(uint2*)(SM + wO3 + l16 + (unsigned)(t3 & 1) * 8u) = wv;
            }
        } else if (wid == 14) {
            if (s >= 3 && s <= TT + 2) { // head for t = s-3
                v8hf C0 = *(const v8hf*)(SM + rO3 + l16);
                v4f o = BH;
                o = MFMA16(WF[0], C0, o);
                if (g == 0)
                    *(float2*)(SM + ORG + (unsigned)col * 512u
                                  + ((unsigned)(s - 3) & 63u) * 8u) =
                        make_float2(o[0], o[1]);
            }
        } else {
            if (s >= 35 && ((s - 35) & 31) == 0) flushfn(s - 35);   // tbase 0..448
        }
        __syncthreads();
        rO1 ^= 4096u; wO1 ^= 4096u;
        rO2 ^= 2048u; wO2 ^= 2048u;
        rO3 ^= 1024u; wO3 ^= 1024u;
    }
    if (wid == 15) flushfn(480);   // head(480..511) ordered by the final barrier
}

extern "C" void kernel_launch(void* const* d_in, const int* in_sizes, int n_in,
                              void* d_out, int out_size, void* d_ws, size_t ws_size,
                              hipStream_t stream) {
    (void)in_sizes; (void)n_in; (void)d_ws; (void)ws_size; (void)out_size;
    const float* x     = (const float*)d_in[0];
    const float* W_ih1 = (const float*)d_in[1];
    const float* W_hh1 = (const float*)d_in[2];
    const float* b_ih1 = (const float*)d_in[3];
    const float* b_hh1 = (const float*)d_in[4];
    const float* W_ih2 = (const float*)d_in[5];
    const float* W_hh2 = (const float*)d_in[6];
    const float* b_ih2 = (const float*)d_in[7];
    const float* b_hh2 = (const float*)d_in[8];
    const float* W_ih3 = (const float*)d_in[9];
    const float* W_hh3 = (const float*)d_in[10];
    const float* b_ih3 = (const float*)d_in[11];
    const float* b_hh3 = (const float*)d_in[12];
    const float* W_o1  = (const float*)d_in[13];
    const float* b_o1  = (const float*)d_in[14];
    const float* W_o2  = (const float*)d_in[15];
    const float* b_o2  = (const float*)d_in[16];
    float* out = (float*)d_out;

    rnn3_nu<<<2048 / BT, NTH, 0, stream>>>(
        x, W_ih1, W_hh1, b_ih1, b_hh1,
        W_ih2, W_hh2, b_ih2, b_hh2,
        W_ih3, W_hh3, b_ih3, b_hh3,
        W_o1, b_o1, W_o2, b_o2, out);
}